// Round 5
// baseline (102.106 us; speedup 1.0000x reference)
//
#include <hip/hip_runtime.h>
#include <stdint.h>

#define NHEADS 16
#define HDIM 64
#define WIN 33
#define BATCH 2
#define SEQ 2048
#define MROWS (BATCH*SEQ)   // 4096
#define PARTSZ (BATCH*NHEADS*SEQ*HDIM)  // 4194304

using f32x4 = __attribute__((ext_vector_type(4))) float;
using bf16x8 = __attribute__((ext_vector_type(8))) short;

__device__ inline short f2bf(float f) {
    union { float f; uint32_t u; } c; c.f = f;
    uint32_t u = c.u;
    uint32_t r = (u + 0x7fffu + ((u >> 16) & 1u)) >> 16;
    return (short)(uint16_t)r;
}
__device__ inline float bf2f(short s) {
    union { uint32_t u; float f; } c; c.u = ((uint32_t)(uint16_t)s) << 16; return c.f;
}

#define GLL16(g, l) __builtin_amdgcn_global_load_lds( \
        (const __attribute__((address_space(1))) void*)(g), \
        (__attribute__((address_space(3))) void*)(l), 16, 0, 0)
#define WAITV(n) asm volatile("s_waitcnt vmcnt(" #n ")" ::: "memory")
#define SBAR()   __builtin_amdgcn_s_barrier()
#define SCHED0() __builtin_amdgcn_sched_barrier(0)

// ---------------- fused f32->bf16 for x, w_qkv, w_out ----------------
// segments (8-elem groups): x 524288 | w_qkv 393216 | w_out 131072
__global__ __launch_bounds__(256)
void cvt3_k(const float* __restrict__ x,  short* __restrict__ xb,
            const float* __restrict__ w1, short* __restrict__ w1b,
            const float* __restrict__ w2, short* __restrict__ w2b)
{
    const int i = blockIdx.x * 256 + threadIdx.x;
    const float* src; short* dstp; int off;
    if (i < 524288)      { src = x;  dstp = xb;  off = i; }
    else if (i < 917504) { src = w1; dstp = w1b; off = i - 524288; }
    else                 { src = w2; dstp = w2b; off = i - 917504; }
    const f32x4 v0 = *(const f32x4*)(src + (size_t)off * 8);
    const f32x4 v1 = *(const f32x4*)(src + (size_t)off * 8 + 4);
    bf16x8 o;
    o[0] = f2bf(v0[0]); o[1] = f2bf(v0[1]); o[2] = f2bf(v0[2]); o[3] = f2bf(v0[3]);
    o[4] = f2bf(v1[0]); o[5] = f2bf(v1[1]); o[6] = f2bf(v1[2]); o[7] = f2bf(v1[3]);
    *(bf16x8*)(dstp + (size_t)off * 8) = o;
}

// ================= GEMM1: qkv projection =================
// C[4096,3072] = A[4096,1024] * B[3072,1024]^T + bias -> bf16 scatter to
// head-major q/k ([bh][s][d]) and transposed v ([bh][d][s]).
// 256x256 tile, BK=32, 8 waves (2x4), 4-deep LDS pipeline, counted vmcnt.
// LDS slot swizzle: 16B slot ^= (row>>1)&3 (uniform bank-set spread, b128 floor);
// staging pre-swizzles the GLOBAL source (global_load_lds dest must be linear).
__global__ __launch_bounds__(512, 1)
void gemm1_k(const short* __restrict__ A, const short* __restrict__ Bm,
             const float* __restrict__ bias, short* __restrict__ dst)
{
    __shared__ short As[4][8192];   // 4 bufs x 256x32 bf16 = 64 KB
    __shared__ short Bs[4][8192];   // 64 KB
    const int tid  = threadIdx.x;
    const int lane = tid & 63;
    const int wave = tid >> 6;
    const int wr = wave >> 2, wc = wave & 3;
    const int q15 = lane & 15, p = lane >> 4;

    int bid = blockIdx.x;                 // 192 blocks, n-major (B-panel shared)
    bid = (bid & 7) * 24 + (bid >> 3);    // XCD-chunked swizzle (192 = 8*24)
    const int tm = (bid % 16) << 8;
    const int tn = (bid / 16) << 8;

    // staging: one call = 512 lanes x 16B = 128 rows x 64B; src slot pre-swizzled
    const int rb  = tid >> 2;             // row 0..127
    const int ssl = (tid & 3) ^ ((tid >> 3) & 3);
    const short* Ag = A  + (size_t)(tm + rb) * 1024 + ssl * 8;
    const short* Bg = Bm + (size_t)(tn + rb) * 1024 + ssl * 8;

#define STAGE1(tt, db) do {                                                  \
        const int _ko = (tt) * 32;                                           \
        GLL16(Ag + _ko,                    &As[db][tid * 8]);                \
        GLL16(Ag + _ko + (size_t)131072,   &As[db][4096 + tid * 8]);         \
        GLL16(Bg + _ko,                    &Bs[db][tid * 8]);                \
        GLL16(Bg + _ko + (size_t)131072,   &Bs[db][4096 + tid * 8]);         \
    } while (0)

    f32x4 acc[8][4];
#pragma unroll
    for (int mi = 0; mi < 8; ++mi)
#pragma unroll
        for (int ni = 0; ni < 4; ++ni) acc[mi][ni] = (f32x4)0.f;

    // frag read offsets (shorts) with the same slot swizzle
    const int sl = p ^ ((q15 >> 1) & 3);
    int oA[8], oB[4];
#pragma unroll
    for (int mi = 0; mi < 8; ++mi) oA[mi] = (wr * 128 + mi * 16 + q15) * 32 + sl * 8;
#pragma unroll
    for (int ni = 0; ni < 4; ++ni) oB[ni] = (wc * 64 + ni * 16 + q15) * 32 + sl * 8;

    STAGE1(0, 0); STAGE1(1, 1); STAGE1(2, 2);
    WAITV(8); SBAR(); SCHED0();           // tile 0 landed for all waves

    for (int t = 0; t < 32; ++t) {
        const int cb = t & 3;
        if (t < 29) STAGE1(t + 3, (t + 3) & 3);   // targets buf freed at barrier t-1
        bf16x8 af[8], bfr[4];
#pragma unroll
        for (int mi = 0; mi < 8; ++mi) af[mi] = *(const bf16x8*)(&As[cb][oA[mi]]);
#pragma unroll
        for (int ni = 0; ni < 4; ++ni) bfr[ni] = *(const bf16x8*)(&Bs[cb][oB[ni]]);
        __builtin_amdgcn_s_setprio(1);
#pragma unroll
        for (int mi = 0; mi < 8; ++mi)
#pragma unroll
            for (int ni = 0; ni < 4; ++ni)
                acc[mi][ni] = __builtin_amdgcn_mfma_f32_16x16x32_bf16(af[mi], bfr[ni], acc[mi][ni], 0, 0, 0);
        __builtin_amdgcn_s_setprio(0);
        SCHED0();
        if (t < 29)      { WAITV(8); SBAR(); SCHED0(); }  // t+1 landed, 8 in flight
        else if (t == 29){ WAITV(4); SBAR(); SCHED0(); }
        else if (t == 30){ WAITV(0); SBAR(); SCHED0(); }
    }
#undef STAGE1

    // epilogue: scatter to q/k [bh][s][d], v^T [bh][d][s]
#pragma unroll
    for (int mi = 0; mi < 8; ++mi) {
#pragma unroll
        for (int ni = 0; ni < 4; ++ni) {
            const int col = tn + wc * 64 + ni * 16 + q15;
            const unsigned h = (unsigned)col / 192u;
            const int c    = col - (int)h * 192;
            const int part = c >> 6;
            const int d    = c & 63;
            const int row0 = tm + wr * 128 + mi * 16 + p * 4;
            const float bv = bias[col];
            const size_t pbase = (size_t)part * PARTSZ;
#pragma unroll
            for (int r = 0; r < 4; ++r) {
                const int row = row0 + r;                  // b*2048 + s
                const int b   = row >> 11;
                const int s   = row & 2047;
                const size_t hb = pbase + ((((size_t)b << 4) + h) << 17);
                const size_t addr = (part == 2)
                    ? hb + ((size_t)d << 11) + s
                    : hb + ((size_t)s << 6) + d;
                dst[addr] = f2bf(acc[mi][ni][r] + bv);
            }
        }
    }
}

// ================= GEMM2: output projection =================
// C[4096,1024] = A[4096,1024] * B[1024,1024]^T + bias (f32 out).
// 128x128 tile, BK=32, 8 waves (2x4, per-wave 64x32), same pipeline.
__global__ __launch_bounds__(512, 1)
void gemm2_k(const short* __restrict__ A, const short* __restrict__ Bm,
             const float* __restrict__ bias, float* __restrict__ C)
{
    __shared__ short As[4][4096];   // 4 x 128x32 = 32 KB
    __shared__ short Bs[4][4096];
    const int tid  = threadIdx.x;
    const int lane = tid & 63;
    const int wave = tid >> 6;
    const int wr = wave >> 2, wc = wave & 3;
    const int q15 = lane & 15, p = lane >> 4;

    int bid = blockIdx.x;                 // 256 blocks, n-major
    bid = (bid & 7) * 32 + (bid >> 3);    // XCD swizzle (256 = 8*32)
    const int tm = (bid & 31) << 7;
    const int tn = (bid >> 5) << 7;

    const int rb  = tid >> 2;             // 0..127
    const int ssl = (tid & 3) ^ ((tid >> 3) & 3);
    const short* Ag = A  + (size_t)(tm + rb) * 1024 + ssl * 8;
    const short* Bg = Bm + (size_t)(tn + rb) * 1024 + ssl * 8;

#define STAGE2(tt, db) do {                              \
        const int _ko = (tt) * 32;                       \
        GLL16(Ag + _ko, &As[db][tid * 8]);               \
        GLL16(Bg + _ko, &Bs[db][tid * 8]);               \
    } while (0)

    f32x4 acc[4][2];
#pragma unroll
    for (int mi = 0; mi < 4; ++mi)
#pragma unroll
        for (int ni = 0; ni < 2; ++ni) acc[mi][ni] = (f32x4)0.f;

    const int sl = p ^ ((q15 >> 1) & 3);
    int oA[4], oB[2];
#pragma unroll
    for (int mi = 0; mi < 4; ++mi) oA[mi] = (wr * 64 + mi * 16 + q15) * 32 + sl * 8;
#pragma unroll
    for (int ni = 0; ni < 2; ++ni) oB[ni] = (wc * 32 + ni * 16 + q15) * 32 + sl * 8;

    STAGE2(0, 0); STAGE2(1, 1); STAGE2(2, 2);
    WAITV(4); SBAR(); SCHED0();

    for (int t = 0; t < 32; ++t) {
        const int cb = t & 3;
        if (t < 29) STAGE2(t + 3, (t + 3) & 3);
        bf16x8 af[4], bfr[2];
#pragma unroll
        for (int mi = 0; mi < 4; ++mi) af[mi] = *(const bf16x8*)(&As[cb][oA[mi]]);
#pragma unroll
        for (int ni = 0; ni < 2; ++ni) bfr[ni] = *(const bf16x8*)(&Bs[cb][oB[ni]]);
        __builtin_amdgcn_s_setprio(1);
#pragma unroll
        for (int mi = 0; mi < 4; ++mi)
#pragma unroll
            for (int ni = 0; ni < 2; ++ni)
                acc[mi][ni] = __builtin_amdgcn_mfma_f32_16x16x32_bf16(af[mi], bfr[ni], acc[mi][ni], 0, 0, 0);
        __builtin_amdgcn_s_setprio(0);
        SCHED0();
        if (t < 29)      { WAITV(4); SBAR(); SCHED0(); }
        else if (t == 29){ WAITV(2); SBAR(); SCHED0(); }
        else if (t == 30){ WAITV(0); SBAR(); SCHED0(); }
    }
#undef STAGE2

#pragma unroll
    for (int mi = 0; mi < 4; ++mi) {
#pragma unroll
        for (int ni = 0; ni < 2; ++ni) {
            const int col  = tn + wc * 32 + ni * 16 + q15;
            const int row0 = tm + wr * 64 + mi * 16 + p * 4;
            const float bv = bias[col];
#pragma unroll
            for (int r = 0; r < 4; ++r)
                C[(size_t)(row0 + r) * 1024 + col] = acc[mi][ni][r] + bv;
        }
    }
}

// ---------------- sliding-window attention via MFMA (unchanged) ----------------
__global__ __launch_bounds__(256)
void swattn4_k(const short* __restrict__ qkvb, short* __restrict__ ctx)
{
    __shared__ short Ks[96 * 64];
    __shared__ short Vt[64 * 104];
    const int tid  = threadIdx.x;
    const int lane = tid & 63;
    const int w    = tid >> 6;
    const int q15  = lane & 15;
    const int p    = lane >> 4;
    const int tile = blockIdx.x & 31;
    const int bh   = blockIdx.x >> 5;
    const int b    = bh >> 4, h = bh & 15;
    const int s0   = tile * 64;
    const short* qbase  = qkvb + ((size_t)bh << 17);
    const short* kbase  = qbase + PARTSZ;
    const short* vtbase = qbase + 2 * PARTSZ;

#pragma unroll
    for (int c = 0; c < 3; ++c) {
        const int idx = c * 256 + tid;
        const int row = idx >> 3;
        const int sli = idx & 7;
        const int pos = s0 - 16 + row;
        bf16x8 kv = (bf16x8)0;
        if (pos >= 0 && pos < SEQ)
            kv = *(const bf16x8*)(kbase + (size_t)pos * 64 + sli * 8);
        *(bf16x8*)(Ks + row * 64 + ((sli ^ (row & 7)) << 3)) = kv;
    }
#pragma unroll
    for (int c = 0; c < 4; ++c) {
        const int idx = c * 256 + tid;
        const int d   = idx >> 4;
        const int sli = idx & 15;
        if (sli < 12) {
            const int pos = s0 - 16 + sli * 8;
            bf16x8 vv = (bf16x8)0;
            if (pos >= 0 && pos <= SEQ - 8)
                vv = *(const bf16x8*)(vtbase + (size_t)d * SEQ + pos);
            *(bf16x8*)(Vt + d * 104 + sli * 8) = vv;
        }
    }
    __syncthreads();

    const int qrow = s0 + w * 16 + q15;
    const bf16x8 qf0 = *(const bf16x8*)(qbase + (size_t)qrow * 64 + p * 8);
    const bf16x8 qf1 = *(const bf16x8*)(qbase + (size_t)qrow * 64 + 32 + p * 8);

    f32x4 accs[6];
#pragma unroll
    for (int t = 0; t < 6; ++t) accs[t] = (f32x4)0.f;
#pragma unroll
    for (int t = 0; t < 6; ++t) {
        const int row = t * 16 + q15;
        const int sw  = row & 7;
        const bf16x8 kf0 = *(const bf16x8*)(Ks + row * 64 + ((p ^ sw) << 3));
        const bf16x8 kf1 = *(const bf16x8*)(Ks + row * 64 + (((p + 4) ^ sw) << 3));
        accs[t] = __builtin_amdgcn_mfma_f32_16x16x32_bf16(kf0, qf0, accs[t], 0, 0, 0);
        accs[t] = __builtin_amdgcn_mfma_f32_16x16x32_bf16(kf1, qf1, accs[t], 0, 0, 0);
    }

    const int qloc = w * 16 + q15;
    float m = -1e30f;
#pragma unroll
    for (int t = 0; t < 6; ++t)
#pragma unroll
        for (int r = 0; r < 4; ++r) {
            const int n = t * 16 + p * 4 + r;
            const bool valid = (n >= qloc) && (n <= qloc + 32);
            const float v = valid ? accs[t][r] * 0.125f : -1e30f;
            accs[t][r] = v;
            m = fmaxf(m, v);
        }
    m = fmaxf(m, __shfl_xor(m, 16));
    m = fmaxf(m, __shfl_xor(m, 32));
    float sum = 0.f;
#pragma unroll
    for (int t = 0; t < 6; ++t)
#pragma unroll
        for (int r = 0; r < 4; ++r) {
            const float e = __expf(accs[t][r] - m);
            accs[t][r] = e;
            sum += e;
        }
    sum += __shfl_xor(sum, 16);
    sum += __shfl_xor(sum, 32);
    const float inv = 1.f / sum;

    uint32_t pk[6][2];
#pragma unroll
    for (int t = 0; t < 6; ++t)
#pragma unroll
        for (int rp = 0; rp < 2; ++rp) {
            const float lo = accs[t][2 * rp] * inv;
            const float hi = accs[t][2 * rp + 1] * inv;
            uint32_t o;
            asm("v_cvt_pk_bf16_f32 %0, %1, %2" : "=v"(o) : "v"(lo), "v"(hi));
            pk[t][rp] = o;
        }
    uint32_t afu[3][4];
#pragma unroll
    for (int t = 0; t < 6; ++t)
#pragma unroll
        for (int rp = 0; rp < 2; ++rp)
#pragma unroll
            for (int bb = 0; bb < 2; ++bb) {
                const int src = q15 + (((2 * p + bb) & 3) << 4);
                const uint32_t v = __shfl((int)pk[t][rp], src);
                if ((t & 1) == (p >> 1))
                    afu[t >> 1][2 * bb + rp] = v;
            }
    union U { uint32_t u[4]; bf16x8 v; };
    U u0, u1, u2;
#pragma unroll
    for (int f = 0; f < 4; ++f) { u0.u[f] = afu[0][f]; u1.u[f] = afu[1][f]; u2.u[f] = afu[2][f]; }
    const bf16x8 af0 = u0.v, af1 = u1.v, af2 = u2.v;

    f32x4 accp[4];
#pragma unroll
    for (int dt = 0; dt < 4; ++dt) accp[dt] = (f32x4)0.f;
#pragma unroll
    for (int dt = 0; dt < 4; ++dt) {
        const short* vr = Vt + (dt * 16 + q15) * 104 + p * 8;
        const bf16x8 vf0 = *(const bf16x8*)(vr);
        const bf16x8 vf1 = *(const bf16x8*)(vr + 32);
        const bf16x8 vf2 = *(const bf16x8*)(vr + 64);
        accp[dt] = __builtin_amdgcn_mfma_f32_16x16x32_bf16(af0, vf0, accp[dt], 0, 0, 0);
        accp[dt] = __builtin_amdgcn_mfma_f32_16x16x32_bf16(af1, vf1, accp[dt], 0, 0, 0);
        accp[dt] = __builtin_amdgcn_mfma_f32_16x16x32_bf16(af2, vf2, accp[dt], 0, 0, 0);
    }

#pragma unroll
    for (int dt = 0; dt < 4; ++dt) {
        const int d = dt * 16 + q15;
#pragma unroll
        for (int r = 0; r < 4; ++r) {
            const int s = s0 + w * 16 + p * 4 + r;
            ctx[(((size_t)(b * SEQ + s)) << 10) + h * 64 + d] = f2bf(accp[dt][r]);
        }
    }
}

// ---------------- launch ----------------
extern "C" void kernel_launch(void* const* d_in, const int* in_sizes, int n_in,
                              void* d_out, int out_size, void* d_ws, size_t ws_size,
                              hipStream_t stream)
{
    const float* x     = (const float*)d_in[0];
    const float* w_qkv = (const float*)d_in[1];
    const float* b_qkv = (const float*)d_in[2];
    const float* w_out = (const float*)d_in[3];
    const float* b_out = (const float*)d_in[4];
    float* out = (float*)d_out;

    char* ws = (char*)d_ws;
    short* x_bf    = (short*)(ws);                       // 8 MB
    short* wqkv_bf = (short*)(ws + (8ull  << 20));       // 6 MB
    short* wout_bf = (short*)(ws + (14ull << 20));       // 2 MB
    short* qkvb    = (short*)(ws + (16ull << 20));       // 24 MB: q,k [bh][s][d]; v^T [bh][d][s]
    short* ctx     = (short*)(ws + (48ull << 20));       // 8 MB

    cvt3_k<<<dim3(4096), 256, 0, stream>>>(x, x_bf, w_qkv, wqkv_bf, w_out, wout_bf);

    gemm1_k<<<dim3(192), 512, 0, stream>>>(x_bf, wqkv_bf, b_qkv, qkvb);

    swattn4_k<<<dim3((SEQ / 64) * BATCH * NHEADS), 256, 0, stream>>>(qkvb, (short*)ctx);

    gemm2_k<<<dim3(256), 512, 0, stream>>>(ctx, wout_bf, b_out, out);
}

// Round 6
// 84.050 us; speedup vs baseline: 1.2148x; 1.2148x over previous
//
#include <hip/hip_runtime.h>
#include <stdint.h>

#define NHEADS 16
#define HDIM 64
#define WIN 33
#define BATCH 2
#define SEQ 2048
#define MROWS (BATCH*SEQ)   // 4096
#define PARTSZ (BATCH*NHEADS*SEQ*HDIM)  // 4194304

using f32x4 = __attribute__((ext_vector_type(4))) float;
using bf16x8 = __attribute__((ext_vector_type(8))) short;

__device__ inline short f2bf(float f) {
    union { float f; uint32_t u; } c; c.f = f;
    uint32_t u = c.u;
    uint32_t r = (u + 0x7fffu + ((u >> 16) & 1u)) >> 16;
    return (short)(uint16_t)r;
}

#define GLL16(g, l) __builtin_amdgcn_global_load_lds( \
        (const __attribute__((address_space(1))) void*)(g), \
        (__attribute__((address_space(3))) void*)(l), 16, 0, 0)
#define WAITV(n) asm volatile("s_waitcnt vmcnt(" #n ")" ::: "memory")
#define SBAR()   __builtin_amdgcn_s_barrier()
#define SCHED0() __builtin_amdgcn_sched_barrier(0)

// ---------------- fused f32->bf16 for x, w_qkv, w_out ----------------
__global__ __launch_bounds__(256)
void cvt3_k(const float* __restrict__ x,  short* __restrict__ xb,
            const float* __restrict__ w1, short* __restrict__ w1b,
            const float* __restrict__ w2, short* __restrict__ w2b)
{
    const int i = blockIdx.x * 256 + threadIdx.x;
    const float* src; short* dstp; int off;
    if (i < 524288)      { src = x;  dstp = xb;  off = i; }
    else if (i < 917504) { src = w1; dstp = w1b; off = i - 524288; }
    else                 { src = w2; dstp = w2b; off = i - 917504; }
    const f32x4 v0 = *(const f32x4*)(src + (size_t)off * 8);
    const f32x4 v1 = *(const f32x4*)(src + (size_t)off * 8 + 4);
    bf16x8 o;
    o[0] = f2bf(v0[0]); o[1] = f2bf(v0[1]); o[2] = f2bf(v0[2]); o[3] = f2bf(v0[3]);
    o[4] = f2bf(v1[0]); o[5] = f2bf(v1[1]); o[6] = f2bf(v1[2]); o[7] = f2bf(v1[3]);
    *(bf16x8*)(dstp + (size_t)off * 8) = o;
}

// ================= GEMM1: qkv projection =================
// C[4096,3072] = A[4096,1024] * B[3072,1024]^T + bias -> bf16 scatter to
// head-major q/k ([bh][s][d]) and transposed v ([bh][d][s]).
// 128x128 tile, BK=32, 4 waves (2x2), 3-deep LDS pipeline (48 KB -> 3 blk/CU),
// counted vmcnt (never 0 in steady state), conflict-free slot swizzle
// (slot ^= (row>>1)&3, measured 0 conflicts in r5), setprio around MFMA.
__global__ __launch_bounds__(256, 3)
void gemm1_k(const short* __restrict__ A, const short* __restrict__ Bm,
             const float* __restrict__ bias, short* __restrict__ dst)
{
    __shared__ short As[3][4096];   // 3 bufs x 128x32 bf16 = 24 KB
    __shared__ short Bs[3][4096];   // 24 KB
    const int tid  = threadIdx.x;
    const int lane = tid & 63;
    const int wave = tid >> 6;
    const int wr = wave >> 1, wc = wave & 1;
    const int q15 = lane & 15, p = lane >> 4;

    int bid = blockIdx.x;                 // 768 blocks
    bid = (bid & 7) * 96 + (bid >> 3);    // bijective XCD-chunked swizzle
    const int tm = (bid & 31) << 7;
    const int tn = (bid >> 5) << 7;

    // staging: call covers 64 rows x 64B; thread t -> row t>>2, 16B slot t&3,
    // source slot pre-swizzled so LDS dest stays linear (rule #21).
    const int rb  = tid >> 2;
    const int ssl = (tid & 3) ^ ((rb >> 1) & 3);
    const short* Ag = A  + (size_t)(tm + rb) * 1024 + ssl * 8;
    const short* Bg = Bm + (size_t)(tn + rb) * 1024 + ssl * 8;

#define STAGE1(tt, db) do {                                  \
        const int _ko = (tt) * 32;                           \
        GLL16(Ag + _ko,         &As[db][tid * 8]);           \
        GLL16(Ag + _ko + 65536, &As[db][2048 + tid * 8]);    \
        GLL16(Bg + _ko,         &Bs[db][tid * 8]);           \
        GLL16(Bg + _ko + 65536, &Bs[db][2048 + tid * 8]);    \
    } while (0)

    f32x4 acc[4][4];
#pragma unroll
    for (int i = 0; i < 4; ++i)
#pragma unroll
        for (int j = 0; j < 4; ++j) acc[i][j] = (f32x4)0.f;

    // frag read offsets with the same slot swizzle
    int oA[4], oB[4];
#pragma unroll
    for (int mi = 0; mi < 4; ++mi) {
        const int row = wr * 64 + mi * 16 + q15;
        oA[mi] = row * 32 + (p ^ ((row >> 1) & 3)) * 8;
    }
#pragma unroll
    for (int ni = 0; ni < 4; ++ni) {
        const int row = wc * 64 + ni * 16 + q15;
        oB[ni] = row * 32 + (p ^ ((row >> 1) & 3)) * 8;
    }

    STAGE1(0, 0); STAGE1(1, 1);
    WAITV(4); SBAR(); SCHED0();           // tile 0 landed block-wide

    for (int t = 0; t < 32; ++t) {
        const int cb = t % 3;
        if (t < 30) STAGE1(t + 2, (t + 2) % 3);   // buf freed at barrier t-1
        bf16x8 af[4], bfr[4];
#pragma unroll
        for (int mi = 0; mi < 4; ++mi) af[mi] = *(const bf16x8*)(&As[cb][oA[mi]]);
#pragma unroll
        for (int ni = 0; ni < 4; ++ni) bfr[ni] = *(const bf16x8*)(&Bs[cb][oB[ni]]);
        __builtin_amdgcn_s_setprio(1);
#pragma unroll
        for (int mi = 0; mi < 4; ++mi)
#pragma unroll
            for (int ni = 0; ni < 4; ++ni)
                acc[mi][ni] = __builtin_amdgcn_mfma_f32_16x16x32_bf16(af[mi], bfr[ni], acc[mi][ni], 0, 0, 0);
        __builtin_amdgcn_s_setprio(0);
        SCHED0();
        if (t < 30)       { WAITV(4); SBAR(); SCHED0(); }  // tile t+1 landed, 4 in flight
        else if (t == 30) { WAITV(0); SBAR(); SCHED0(); }
    }
#undef STAGE1

    // epilogue: scatter to q/k [bh][s][d], v^T [bh][d][s]
#pragma unroll
    for (int mi = 0; mi < 4; ++mi) {
#pragma unroll
        for (int ni = 0; ni < 4; ++ni) {
            const int col = tn + wc * 64 + ni * 16 + q15;
            const unsigned h = (unsigned)col / 192u;
            const int c    = col - (int)h * 192;
            const int part = c >> 6;
            const int d    = c & 63;
            const int row0 = tm + wr * 64 + mi * 16 + p * 4;
            const float bv = bias[col];
            const size_t pbase = (size_t)part * PARTSZ;
#pragma unroll
            for (int r = 0; r < 4; ++r) {
                const int row = row0 + r;                  // b*2048 + s
                const int b   = row >> 11;
                const int s   = row & 2047;
                const size_t hb = pbase + ((((size_t)b << 4) + h) << 17);
                const size_t addr = (part == 2)
                    ? hb + ((size_t)d << 11) + s
                    : hb + ((size_t)s << 6) + d;
                dst[addr] = f2bf(acc[mi][ni][r] + bv);
            }
        }
    }
}

// ================= GEMM2: output projection =================
// C[4096,1024] = A[4096,1024] * B[1024,1024]^T + bias (f32 out).
// 64x128 tile, 4 waves (1x4, per-wave 64x32), 3-deep pipeline, 36 KB LDS.
__global__ __launch_bounds__(256, 3)
void gemm2_k(const short* __restrict__ A, const short* __restrict__ Bm,
             const float* __restrict__ bias, float* __restrict__ C)
{
    __shared__ short As[3][2048];   // 3 x 64x32 = 12 KB
    __shared__ short Bs[3][4096];   // 3 x 128x32 = 24 KB
    const int tid  = threadIdx.x;
    const int lane = tid & 63;
    const int wc   = tid >> 6;      // wave = n-quarter
    const int q15 = lane & 15, p = lane >> 4;

    int bid = blockIdx.x;                 // 512 blocks
    bid = (bid & 7) * 64 + (bid >> 3);    // bijective XCD swizzle
    const int tm = (bid & 63) << 6;
    const int tn = (bid >> 6) << 7;

    const int rb  = tid >> 2;
    const int ssl = (tid & 3) ^ ((rb >> 1) & 3);
    const short* Ag = A  + (size_t)(tm + rb) * 1024 + ssl * 8;
    const short* Bg = Bm + (size_t)(tn + rb) * 1024 + ssl * 8;

#define STAGE2(tt, db) do {                                  \
        const int _ko = (tt) * 32;                           \
        GLL16(Ag + _ko,         &As[db][tid * 8]);           \
        GLL16(Bg + _ko,         &Bs[db][tid * 8]);           \
        GLL16(Bg + _ko + 65536, &Bs[db][2048 + tid * 8]);    \
    } while (0)

    f32x4 acc[4][2];
#pragma unroll
    for (int mi = 0; mi < 4; ++mi)
#pragma unroll
        for (int ni = 0; ni < 2; ++ni) acc[mi][ni] = (f32x4)0.f;

    int oA[4], oB[2];
#pragma unroll
    for (int mi = 0; mi < 4; ++mi) {
        const int row = mi * 16 + q15;
        oA[mi] = row * 32 + (p ^ ((row >> 1) & 3)) * 8;
    }
#pragma unroll
    for (int ni = 0; ni < 2; ++ni) {
        const int row = wc * 32 + ni * 16 + q15;
        oB[ni] = row * 32 + (p ^ ((row >> 1) & 3)) * 8;
    }

    STAGE2(0, 0); STAGE2(1, 1);
    WAITV(3); SBAR(); SCHED0();

    for (int t = 0; t < 32; ++t) {
        const int cb = t % 3;
        if (t < 30) STAGE2(t + 2, (t + 2) % 3);
        bf16x8 af[4], bfr[2];
#pragma unroll
        for (int mi = 0; mi < 4; ++mi) af[mi] = *(const bf16x8*)(&As[cb][oA[mi]]);
#pragma unroll
        for (int ni = 0; ni < 2; ++ni) bfr[ni] = *(const bf16x8*)(&Bs[cb][oB[ni]]);
        __builtin_amdgcn_s_setprio(1);
#pragma unroll
        for (int mi = 0; mi < 4; ++mi)
#pragma unroll
            for (int ni = 0; ni < 2; ++ni)
                acc[mi][ni] = __builtin_amdgcn_mfma_f32_16x16x32_bf16(af[mi], bfr[ni], acc[mi][ni], 0, 0, 0);
        __builtin_amdgcn_s_setprio(0);
        SCHED0();
        if (t < 30)       { WAITV(3); SBAR(); SCHED0(); }
        else if (t == 30) { WAITV(0); SBAR(); SCHED0(); }
    }
#undef STAGE2

#pragma unroll
    for (int mi = 0; mi < 4; ++mi) {
#pragma unroll
        for (int ni = 0; ni < 2; ++ni) {
            const int col  = tn + wc * 32 + ni * 16 + q15;
            const int row0 = tm + mi * 16 + p * 4;
            const float bv = bias[col];
#pragma unroll
            for (int r = 0; r < 4; ++r)
                C[(size_t)(row0 + r) * 1024 + col] = acc[mi][ni][r] + bv;
        }
    }
}

// ---------------- sliding-window attention via MFMA (unchanged, r4-verified) ----------------
__global__ __launch_bounds__(256)
void swattn4_k(const short* __restrict__ qkvb, short* __restrict__ ctx)
{
    __shared__ short Ks[96 * 64];
    __shared__ short Vt[64 * 104];
    const int tid  = threadIdx.x;
    const int lane = tid & 63;
    const int w    = tid >> 6;
    const int q15  = lane & 15;
    const int p    = lane >> 4;
    const int tile = blockIdx.x & 31;
    const int bh   = blockIdx.x >> 5;
    const int b    = bh >> 4, h = bh & 15;
    const int s0   = tile * 64;
    const short* qbase  = qkvb + ((size_t)bh << 17);
    const short* kbase  = qbase + PARTSZ;
    const short* vtbase = qbase + 2 * PARTSZ;

#pragma unroll
    for (int c = 0; c < 3; ++c) {
        const int idx = c * 256 + tid;
        const int row = idx >> 3;
        const int sli = idx & 7;
        const int pos = s0 - 16 + row;
        bf16x8 kv = (bf16x8)0;
        if (pos >= 0 && pos < SEQ)
            kv = *(const bf16x8*)(kbase + (size_t)pos * 64 + sli * 8);
        *(bf16x8*)(Ks + row * 64 + ((sli ^ (row & 7)) << 3)) = kv;
    }
#pragma unroll
    for (int c = 0; c < 4; ++c) {
        const int idx = c * 256 + tid;
        const int d   = idx >> 4;
        const int sli = idx & 15;
        if (sli < 12) {
            const int pos = s0 - 16 + sli * 8;
            bf16x8 vv = (bf16x8)0;
            if (pos >= 0 && pos <= SEQ - 8)
                vv = *(const bf16x8*)(vtbase + (size_t)d * SEQ + pos);
            *(bf16x8*)(Vt + d * 104 + sli * 8) = vv;
        }
    }
    __syncthreads();

    const int qrow = s0 + w * 16 + q15;
    const bf16x8 qf0 = *(const bf16x8*)(qbase + (size_t)qrow * 64 + p * 8);
    const bf16x8 qf1 = *(const bf16x8*)(qbase + (size_t)qrow * 64 + 32 + p * 8);

    f32x4 accs[6];
#pragma unroll
    for (int t = 0; t < 6; ++t) accs[t] = (f32x4)0.f;
#pragma unroll
    for (int t = 0; t < 6; ++t) {
        const int row = t * 16 + q15;
        const int sw  = row & 7;
        const bf16x8 kf0 = *(const bf16x8*)(Ks + row * 64 + ((p ^ sw) << 3));
        const bf16x8 kf1 = *(const bf16x8*)(Ks + row * 64 + (((p + 4) ^ sw) << 3));
        accs[t] = __builtin_amdgcn_mfma_f32_16x16x32_bf16(kf0, qf0, accs[t], 0, 0, 0);
        accs[t] = __builtin_amdgcn_mfma_f32_16x16x32_bf16(kf1, qf1, accs[t], 0, 0, 0);
    }

    const int qloc = w * 16 + q15;
    float m = -1e30f;
#pragma unroll
    for (int t = 0; t < 6; ++t)
#pragma unroll
        for (int r = 0; r < 4; ++r) {
            const int n = t * 16 + p * 4 + r;
            const bool valid = (n >= qloc) && (n <= qloc + 32);
            const float v = valid ? accs[t][r] * 0.125f : -1e30f;
            accs[t][r] = v;
            m = fmaxf(m, v);
        }
    m = fmaxf(m, __shfl_xor(m, 16));
    m = fmaxf(m, __shfl_xor(m, 32));
    float sum = 0.f;
#pragma unroll
    for (int t = 0; t < 6; ++t)
#pragma unroll
        for (int r = 0; r < 4; ++r) {
            const float e = __expf(accs[t][r] - m);
            accs[t][r] = e;
            sum += e;
        }
    sum += __shfl_xor(sum, 16);
    sum += __shfl_xor(sum, 32);
    const float inv = 1.f / sum;

    uint32_t pk[6][2];
#pragma unroll
    for (int t = 0; t < 6; ++t)
#pragma unroll
        for (int rp = 0; rp < 2; ++rp) {
            const float lo = accs[t][2 * rp] * inv;
            const float hi = accs[t][2 * rp + 1] * inv;
            uint32_t o;
            asm("v_cvt_pk_bf16_f32 %0, %1, %2" : "=v"(o) : "v"(lo), "v"(hi));
            pk[t][rp] = o;
        }
    uint32_t afu[3][4];
#pragma unroll
    for (int t = 0; t < 6; ++t)
#pragma unroll
        for (int rp = 0; rp < 2; ++rp)
#pragma unroll
            for (int bb = 0; bb < 2; ++bb) {
                const int src = q15 + (((2 * p + bb) & 3) << 4);
                const uint32_t v = __shfl((int)pk[t][rp], src);
                if ((t & 1) == (p >> 1))
                    afu[t >> 1][2 * bb + rp] = v;
            }
    union U { uint32_t u[4]; bf16x8 v; };
    U u0, u1, u2;
#pragma unroll
    for (int f = 0; f < 4; ++f) { u0.u[f] = afu[0][f]; u1.u[f] = afu[1][f]; u2.u[f] = afu[2][f]; }
    const bf16x8 af0 = u0.v, af1 = u1.v, af2 = u2.v;

    f32x4 accp[4];
#pragma unroll
    for (int dt = 0; dt < 4; ++dt) accp[dt] = (f32x4)0.f;
#pragma unroll
    for (int dt = 0; dt < 4; ++dt) {
        const short* vr = Vt + (dt * 16 + q15) * 104 + p * 8;
        const bf16x8 vf0 = *(const bf16x8*)(vr);
        const bf16x8 vf1 = *(const bf16x8*)(vr + 32);
        const bf16x8 vf2 = *(const bf16x8*)(vr + 64);
        accp[dt] = __builtin_amdgcn_mfma_f32_16x16x32_bf16(af0, vf0, accp[dt], 0, 0, 0);
        accp[dt] = __builtin_amdgcn_mfma_f32_16x16x32_bf16(af1, vf1, accp[dt], 0, 0, 0);
        accp[dt] = __builtin_amdgcn_mfma_f32_16x16x32_bf16(af2, vf2, accp[dt], 0, 0, 0);
    }

#pragma unroll
    for (int dt = 0; dt < 4; ++dt) {
        const int d = dt * 16 + q15;
#pragma unroll
        for (int r = 0; r < 4; ++r) {
            const int s = s0 + w * 16 + p * 4 + r;
            ctx[(((size_t)(b * SEQ + s)) << 10) + h * 64 + d] = f2bf(accp[dt][r]);
        }
    }
}

// ---------------- launch ----------------
extern "C" void kernel_launch(void* const* d_in, const int* in_sizes, int n_in,
                              void* d_out, int out_size, void* d_ws, size_t ws_size,
                              hipStream_t stream)
{
    const float* x     = (const float*)d_in[0];
    const float* w_qkv = (const float*)d_in[1];
    const float* b_qkv = (const float*)d_in[2];
    const float* w_out = (const float*)d_in[3];
    const float* b_out = (const float*)d_in[4];
    float* out = (float*)d_out;

    char* ws = (char*)d_ws;
    short* x_bf    = (short*)(ws);                       // 8 MB
    short* wqkv_bf = (short*)(ws + (8ull  << 20));       // 6 MB
    short* wout_bf = (short*)(ws + (14ull << 20));       // 2 MB
    short* qkvb    = (short*)(ws + (16ull << 20));       // 24 MB: q,k [bh][s][d]; v^T [bh][d][s]
    short* ctx     = (short*)(ws + (48ull << 20));       // 8 MB

    cvt3_k<<<dim3(4096), 256, 0, stream>>>(x, x_bf, w_qkv, wqkv_bf, w_out, wout_bf);

    gemm1_k<<<dim3(768), 256, 0, stream>>>(x_bf, wqkv_bf, b_qkv, qkvb);

    swattn4_k<<<dim3((SEQ / 64) * BATCH * NHEADS), 256, 0, stream>>>(qkvb, (short*)ctx);

    gemm2_k<<<dim3(512), 256, 0, stream>>>(ctx, wout_bf, b_out, out);
}